// Round 10
// baseline (167.339 us; speedup 1.0000x reference)
//
#include <hip/hip_runtime.h>
#include <math.h>

typedef _Float16 half_t;
typedef _Float16 half4 __attribute__((ext_vector_type(4)));
typedef _Float16 half8 __attribute__((ext_vector_type(8)));
typedef float f32x4 __attribute__((ext_vector_type(4)));

#define LOG2E 1.44269504088896f

// async global -> LDS, 16 B per lane; lds base wave-uniform, lane i at base+i*16.
__device__ __forceinline__ void gload16(const void* g, void* l) {
    __builtin_amdgcn_global_load_lds(
        (const __attribute__((address_space(1))) unsigned int*)g,
        (__attribute__((address_space(3))) unsigned int*)l, 16, 0, 0);
}

// raw v_exp_f32 (inputs are max-shifted <= 0; denorm-flush is harmless here)
__device__ __forceinline__ float fast_exp2(float x) {
    return __builtin_amdgcn_exp2f(x);
}

// ---------------------------------------------------------------------------
// prep (fused): blocks 0..4095 convert hs fp32->fp16; blocks 4096.. build
// group-reduced effective weights (fp16) + log2-domain bias table (fp32).
// ---------------------------------------------------------------------------
__global__ __launch_bounds__(256) void prep(const float* __restrict__ hs,
                     const float* __restrict__ Wq, const float* __restrict__ Wk,
                     const float* __restrict__ Wv, const float* __restrict__ Wo,
                     const float* __restrict__ rb,
                     half_t* __restrict__ hsh,
                     half_t* __restrict__ Wqkv, half_t* __restrict__ Wo_e,
                     float* __restrict__ btab) {
    if (blockIdx.x < 4096) {
        int i = (blockIdx.x * 256 + threadIdx.x) * 8;
        f32x4 a = *(const f32x4*)&hs[i];
        f32x4 b = *(const f32x4*)&hs[i + 4];
        half8 o;
        #pragma unroll
        for (int j = 0; j < 4; ++j) { o[j] = (half_t)a[j]; o[4 + j] = (half_t)b[j]; }
        *(half8*)&hsh[i] = o;
        return;
    }
    int idx = (blockIdx.x - 4096) * 256 + threadIdx.x;
    if (idx < 768 * 1024) {
        int row = idx >> 10, col = idx & 1023;
        int sec = row >> 8;
        int r = row & 255;
        int h = r >> 6, d = r & 63;
        const float* W = (sec == 0) ? Wq : ((sec == 1) ? Wk : Wv);
        float s = 0.f;
        #pragma unroll
        for (int g = 0; g < 4; ++g) s += W[((g * 4 + h) * 64 + d) * 1024 + col];
        s *= (sec == 0) ? LOG2E : 0.25f;   // fold log2e into q-projection
        Wqkv[idx] = (half_t)s;
    }
    if (idx < 1024 * 256) {
        int m = idx >> 8, c = idx & 255;
        float s = 0.f;
        #pragma unroll
        for (int g = 0; g < 4; ++g) s += Wo[m * 1024 + g * 256 + c];
        Wo_e[idx] = (half_t)s;
    }
    if (idx < 4 * 4096) {
        int h = idx >> 12, dpos = idx & 4095;
        int delta = dpos - 2048;
        int bucket = (delta > 0) ? 16 : 0;
        int ad = delta < 0 ? -delta : delta;
        if (ad < 8) bucket += ad;
        else {
            int large = 8 + (int)(logf((float)ad * 0.125f) / logf(16.0f) * 8.0f);
            bucket += (large < 15) ? large : 15;
        }
        float s = 0.f;
        #pragma unroll
        for (int g = 0; g < 4; ++g) s += rb[bucket * 16 + g * 4 + h];
        btab[idx] = s * 0.25f * LOG2E;     // log2-domain bias
    }
}

// ---------------------------------------------------------------------------
// MFMA NT GEMM: C[M,N] = A[M,K]*B[N,K]^T, fp16 in. 128xBN tile, 4 waves of
// 64x(BN/2), BK=64. Double-buffered LDS, single barrier + vmcnt(0) per
// K-step, prefetch issued before compute.
// BN=128: 32 MFMA : 16 ds_read_b128 per wave per K-step (m97-like density),
// LDS 64KB -> 2 blocks/CU.
// 1D grid, y-panel XCD clustering: rowBase = (flat & 63)*128.
// If vtp != null and colBase >= 512 (the V column range), the result is
// written TRANSPOSED to vt[(b*4+h)*64+d][n'] (fuses transpose_v), with the
// token index PERMUTED within each 64-token tile: t[5:4] <-> t[3:2]
// (involution). This makes attn's PV LDS reads conflict-free b128s.
// ---------------------------------------------------------------------------
template <int BN>
__global__ __launch_bounds__(256) void gemm_nt_mfma(const half_t* __restrict__ A,
                                                    const half_t* __restrict__ B,
                                                    void* __restrict__ Cptr,
                                                    int N, int K, int store_half,
                                                    half_t* __restrict__ vtp) {
    constexpr int JN = BN / 32;               // col frags per wave
    __shared__ __attribute__((aligned(16))) half_t As[2][128 * 64];
    __shared__ __attribute__((aligned(16))) half_t Bs[2][BN * 64];
    int tid = threadIdx.x;
    int w = tid >> 6, lane = tid & 63;
    int c = lane & 15, quad = lane >> 4;
    int flat = blockIdx.x;
    int rowBase = (flat & 63) * 128;          // same A-panel -> same XCD
    int colBase = (flat >> 6) * BN;
    int wr = (w & 1) * 64, wc = (w >> 1) * (16 * JN);

    f32x4 acc[4][JN];
    #pragma unroll
    for (int i = 0; i < 4; ++i)
        #pragma unroll
        for (int j = 0; j < JN; ++j) acc[i][j] = (f32x4)(0.f);

    int srow = tid >> 3;                          // 0..31
    int kcs = ((tid & 7) ^ (srow & 7)) * 8;       // swizzled source k-chunk
    int rx = c & 7;
    int nsteps = K >> 6;

    auto stage = [&](int ks) {
        int bb = ks & 1;
        #pragma unroll
        for (int p = 0; p < 4; ++p)
            gload16(&A[(size_t)(rowBase + srow + 32 * p) * K + ks * 64 + kcs],
                    &As[bb][p * 2048 + w * 512]);
        #pragma unroll
        for (int p = 0; p < BN / 32; ++p)
            gload16(&B[(size_t)(colBase + srow + 32 * p) * K + ks * 64 + kcs],
                    &Bs[bb][p * 2048 + w * 512]);
    };

    stage(0);
    __syncthreads();

    for (int ks = 0; ks < nsteps; ++ks) {
        if (ks + 1 < nsteps) stage(ks + 1);       // prefetch into other buffer
        const half_t* Ab = As[ks & 1];
        const half_t* Bb = Bs[ks & 1];
        __builtin_amdgcn_s_setprio(1);
        #pragma unroll
        for (int kh = 0; kh < 2; ++kh) {
            int xk = ((quad + 4 * kh) ^ rx) * 8;
            half8 af[4], bf[JN];
            #pragma unroll
            for (int i = 0; i < 4; ++i)
                af[i] = *(const half8*)&Ab[(wr + i * 16 + c) * 64 + xk];
            #pragma unroll
            for (int j = 0; j < JN; ++j)
                bf[j] = *(const half8*)&Bb[(wc + j * 16 + c) * 64 + xk];
            #pragma unroll
            for (int i = 0; i < 4; ++i)
                #pragma unroll
                for (int j = 0; j < JN; ++j)
                    acc[i][j] = __builtin_amdgcn_mfma_f32_16x16x32_f16(af[i], bf[j], acc[i][j], 0, 0, 0);
        }
        __builtin_amdgcn_s_setprio(0);
        __asm__ __volatile__("s_waitcnt vmcnt(0)" ::: "memory");
        __builtin_amdgcn_s_barrier();
    }

    if (vtp && colBase >= 512) {
        #pragma unroll
        for (int i = 0; i < 4; ++i)
            #pragma unroll
            for (int j = 0; j < JN; ++j) {
                int row0 = rowBase + wr + i * 16 + quad * 4;   // 4 consecutive tokens
                int vcol = colBase - 512 + wc + j * 16 + c;
                int hh = vcol >> 6, dd = vcol & 63;
                int b = row0 >> 11, n0 = row0 & 2047;
                int t = n0 & 63;                               // multiple of 4
                int np = (n0 & ~63) | (((t >> 2) & 3) << 4) | (((t >> 4) & 3) << 2);
                half4 pk;
                #pragma unroll
                for (int reg = 0; reg < 4; ++reg) pk[reg] = (half_t)acc[i][j][reg];
                *(half4*)&vtp[((size_t)((b * 4 + hh) * 64 + dd)) * 2048 + np] = pk;
            }
        return;
    }

    #pragma unroll
    for (int i = 0; i < 4; ++i)
        #pragma unroll
        for (int j = 0; j < JN; ++j)
            #pragma unroll
            for (int reg = 0; reg < 4; ++reg) {
                size_t row = rowBase + wr + i * 16 + quad * 4 + reg;
                size_t col = colBase + wc + j * 16 + c;
                if (store_half) ((half_t*)Cptr)[row * N + col] = (half_t)acc[i][j][reg];
                else            ((float*)Cptr)[row * N + col] = acc[i][j][reg];
            }
}

// ---------------------------------------------------------------------------
// Split-K flash attention, S^T + O^T, per-lane online softmax, register-P
// (PV via mfma_f32_16x16x16_f16, B-operand = exp'd S^T chunk in-lane).
// R7 structure exactly (best measured: 42.9 us):
//  * V tiles stored token-PERMUTED (t[5:4]<->t[3:2], written by the QKV GEMM)
//    -> PV reads are 2 x ds_read_b128 per db (2-way banks = free).
//  * Split counted-vmcnt (T4): stage issues K loads then V loads; mid-iter
//    vmcnt(4)+barrier gates PV on old V only; bottom vmcnt(2)+barrier gates
//    next QK on K only (V stays in flight). No exposed latency.
// K/V double-buffered, LDS = 32768 B -> 4 blocks/CU.
// 1D grid with XCD group clustering: g = flat & 31 encodes (h, b, s).
//  S^T = K Q^T -> D[key, q=c];  O^T = V^T P^T -> D[d, q=c].
// ---------------------------------------------------------------------------
__global__ __launch_bounds__(256) void attn(const half_t* __restrict__ qkv,
                                            const half_t* __restrict__ vt,
                                            const float* __restrict__ btab,
                                            half_t* __restrict__ Opart,
                                            float* __restrict__ ml) {
    __shared__ __attribute__((aligned(16))) half_t Ks[2][64 * 64];
    __shared__ __attribute__((aligned(16))) half_t Vts[2][64 * 64];

    int tid = threadIdx.x;
    int w = tid >> 6, lane = tid & 63;
    int c = lane & 15, quad = lane >> 4;
    int flat = blockIdx.x;
    int g = flat & 31;                 // group id: same group -> same XCD
    int qt = flat >> 5;
    int h = g & 3;
    int zz = g >> 2;
    int b = zz >> 1, s = zz & 1;
    int q0 = qt * 64;
    int bh = b * 4 + h;
    int k0g = s * 1024;

    // Q fragments (B-operand: n=q=c, k=quad*8+j), pre-scaled by log2e
    const half_t* qrow = qkv + (size_t)(b * 2048 + q0 + w * 16 + c) * 768 + h * 64;
    half8 qf0 = *(const half8*)(qrow + quad * 8);
    half8 qf1 = *(const half8*)(qrow + 32 + quad * 8);

    // far-field bias constants (bucket saturates for |delta|>=128)
    float cpos = btab[h * 4096 + 4095];
    float cneg = btab[h * 4096];

    // near-tile bias base: btab[h][ (k - q) + 2048 ], k = ktg + koff
    const float* bpt = btab + h * 4096 + 2048 + k0g - (q0 + w * 16 + c);

    // staging: srow = tid>>3 (0..31, +32 on 2nd instr), chunk tid&7,
    // source chunk xor-swizzled by row&7.
    int srow = tid >> 3;
    int kcs = ((tid & 7) ^ (srow & 7)) * 8;
    const half_t* gK = qkv + (size_t)(b * 2048 + k0g + srow) * 768 + 256 + h * 64 + kcs;
    const half_t* gV = vt + (size_t)(bh * 64 + srow) * 2048 + k0g + kcs;

    // issue order matters: K loads first (bottom vmcnt(2) leaves V in flight)
    auto stage = [&](int it2) {
        int bb = it2 & 1;
        const half_t* gKt = gK + (size_t)(it2 * 64) * 768;
        const half_t* gVt = gV + it2 * 64;
        gload16(gKt,                     &Ks[bb][w * 512]);
        gload16(gKt + (size_t)32 * 768,  &Ks[bb][2048 + w * 512]);
        gload16(gVt,                     &Vts[bb][w * 512]);
        gload16(gVt + 32 * 2048,         &Vts[bb][2048 + w * 512]);
    };

    f32x4 O[4];
    #pragma unroll
    for (int i = 0; i < 4; ++i) O[i] = (f32x4)(0.f);
    float mrow = -1e30f, lrow = 0.f;

    int rx = c & 7;

    // prologue: tile 0 staged, full drain once.
    stage(0);
    __syncthreads();

    for (int it = 0; it < 16; ++it) {
        int ktg = k0g + it * 64;
        if (it < 15) stage(it + 1);               // prefetch into other buffer
        const half_t* Kb = Ks[it & 1];
        const half_t* Vb = Vts[it & 1];

        // S^T = K Q^T : D[key = kb*16 + quad*4+rg, q = c]
        f32x4 ST[4];
        __builtin_amdgcn_s_setprio(1);
        #pragma unroll
        for (int kb = 0; kb < 4; ++kb) {
            int row = kb * 16 + c;
            half8 kf0 = *(const half8*)&Kb[row * 64 + (quad ^ rx) * 8];
            half8 kf1 = *(const half8*)&Kb[row * 64 + ((quad + 4) ^ rx) * 8];
            f32x4 a = (f32x4)(0.f);
            a = __builtin_amdgcn_mfma_f32_16x16x32_f16(kf0, qf0, a, 0, 0, 0);
            a = __builtin_amdgcn_mfma_f32_16x16x32_f16(kf1, qf1, a, 0, 0, 0);
            ST[kb] = a;
        }
        __builtin_amdgcn_s_setprio(0);

        // bias: near tiles gather from btab (L2-resident); far tiles fold
        // the saturated constant cb into madj.
        float cb;
        if (ktg >= q0 + 191) {
            cb = cpos;
        } else if (ktg + 191 <= q0) {
            cb = cneg;
        } else {
            cb = 0.f;
            const float* bp = bpt + it * 64;
            #pragma unroll
            for (int kb = 0; kb < 4; ++kb)
                #pragma unroll
                for (int rg = 0; rg < 4; ++rg)
                    ST[kb][rg] += bp[kb * 16 + quad * 4 + rg];
        }

        // tile max: in-lane 16 keys + 2 swizzles (lanes sharing q = c)
        float tmax = -1e30f;
        #pragma unroll
        for (int kb = 0; kb < 4; ++kb)
            #pragma unroll
            for (int rg = 0; rg < 4; ++rg) tmax = fmaxf(tmax, ST[kb][rg]);
        tmax += cb;
        tmax = fmaxf(tmax, __shfl_xor(tmax, 16));
        tmax = fmaxf(tmax, __shfl_xor(tmax, 32));

        float mnew = fmaxf(mrow, tmax);
        float alpha = fast_exp2(mrow - mnew);     // per-lane scalar
        mrow = mnew;
        float madj = mnew - cb;

        // p = exp2(S - madj) (max-shifted: fp16-safe), kept IN REGISTERS:
        // pc[kb] is directly the B-operand of PV MFMA #kb (k=quad*4+i, col=c).
        half4 pc[4];
        float lsum = 0.f;
        #pragma unroll
        for (int kb = 0; kb < 4; ++kb) {
            #pragma unroll
            for (int rg = 0; rg < 4; ++rg) {
                float p = fast_exp2(ST[kb][rg] - madj);
                lsum += p;
                pc[kb][rg] = (half_t)p;
            }
        }
        lrow = lrow * alpha + lsum;               // in-lane (shared m)

        // mid sync: own old-V done (4 new loads stay in flight), then all waves
        if (it < 15) { __asm__ __volatile__("s_waitcnt vmcnt(4)" ::: "memory"); }
        else         { __asm__ __volatile__("s_waitcnt vmcnt(0)" ::: "memory"); }
        __builtin_amdgcn_s_barrier();

        // O^T[d, q=c] += V^T P^T via 16x16x16 MFMA. V tile is token-permuted
        // (p = quad*16 + kb*4 + i holds original k = kb*16 + quad*4 + i), so
        // each lane's 16 needed halfs are 2 b128 reads (chunks 2q^rx, 2q+1^rx).
        __builtin_amdgcn_s_setprio(1);
        #pragma unroll
        for (int db = 0; db < 4; ++db) {
            const half_t* vrow = &Vb[(db * 16 + c) * 64];
            half8 v01 = *(const half8*)&vrow[((quad * 2) ^ rx) * 8];       // kb=0,1
            half8 v23 = *(const half8*)&vrow[((quad * 2 + 1) ^ rx) * 8];   // kb=2,3
            f32x4 o = O[db];
            #pragma unroll
            for (int rg = 0; rg < 4; ++rg) o[rg] *= alpha;      // per-lane alpha
            o = __builtin_amdgcn_mfma_f32_16x16x16f16(
                    __builtin_shufflevector(v01, v01, 0, 1, 2, 3), pc[0], o, 0, 0, 0);
            o = __builtin_amdgcn_mfma_f32_16x16x16f16(
                    __builtin_shufflevector(v01, v01, 4, 5, 6, 7), pc[1], o, 0, 0, 0);
            o = __builtin_amdgcn_mfma_f32_16x16x16f16(
                    __builtin_shufflevector(v23, v23, 0, 1, 2, 3), pc[2], o, 0, 0, 0);
            o = __builtin_amdgcn_mfma_f32_16x16x16f16(
                    __builtin_shufflevector(v23, v23, 4, 5, 6, 7), pc[3], o, 0, 0, 0);
            O[db] = o;
        }
        __builtin_amdgcn_s_setprio(0);

        // bottom sync: own K(it+1) done (V(it+1) stays in flight), then all waves
        if (it < 15) {
            __asm__ __volatile__("s_waitcnt vmcnt(2)" ::: "memory");
            __builtin_amdgcn_s_barrier();
        }
    }

    // total l across the 4 quad-lanes (same final m), normalize, store
    lrow += __shfl_xor(lrow, 16);
    lrow += __shfl_xor(lrow, 32);
    float inv = 1.0f / lrow;

    int pb = (bh * 32 + qt) * 2 + s;
    #pragma unroll
    for (int db = 0; db < 4; ++db) {
        half4 pk;
        #pragma unroll
        for (int rg = 0; rg < 4; ++rg) pk[rg] = (half_t)(O[db][rg] * inv);
        *(half4*)&Opart[((size_t)pb * 64 + w * 16 + c) * 64 + db * 16 + quad * 4] = pk;
    }
    if (quad == 0) {
        ml[pb * 128 + w * 16 + c] = mrow;
        ml[pb * 128 + 64 + w * 16 + c] = lrow;
    }
}

// ---------------------------------------------------------------------------
// merge the two split-K partials -> ab[b*2048+n][h*64+d]
// Partials normalized: out = (w1*O1 + w2*O2), w_i = 2^(m_i-m) * l_i / Z.
// ---------------------------------------------------------------------------
__global__ __launch_bounds__(256) void merge(const half_t* __restrict__ Opart,
                                             const float* __restrict__ ml,
                                             half_t* __restrict__ ab) {
    int bq = blockIdx.x;            // bh*32 + qt
    int bh = bq >> 5, qt = bq & 31;
    int b = bh >> 2, h = bh & 3;
    int row = threadIdx.x >> 2;
    int cg = (threadIdx.x & 3) * 16;
    int p0 = bq * 2, p1 = p0 + 1;
    float m1 = ml[p0 * 128 + row], l1 = ml[p0 * 128 + 64 + row];
    float m2 = ml[p1 * 128 + row], l2 = ml[p1 * 128 + 64 + row];
    float m = fmaxf(m1, m2);
    float a1 = __builtin_amdgcn_exp2f(m1 - m) * l1;
    float a2 = __builtin_amdgcn_exp2f(m2 - m) * l2;
    float inv = 1.f / (a1 + a2);
    float w1 = a1 * inv, w2 = a2 * inv;
    const half8* o1 = (const half8*)&Opart[((size_t)p0 * 64 + row) * 64 + cg];
    const half8* o2 = (const half8*)&Opart[((size_t)p1 * 64 + row) * 64 + cg];
    half_t* dst = ab + (size_t)(b * 2048 + qt * 64 + row) * 256 + h * 64 + cg;
    #pragma unroll
    for (int v = 0; v < 2; ++v) {
        half8 x = o1[v], y = o2[v], o;
        #pragma unroll
        for (int j = 0; j < 8; ++j)
            o[j] = (half_t)((float)x[j] * w1 + (float)y[j] * w2);
        *(half8*)(dst + v * 8) = o;
    }
}

// ---------------------------------------------------------------------------
// Launch. ws: Wqkv 1.5M | Wo_e .5M | btab 64K | hsh 16M | qkv 12M | vt 4M
// hsh region reused after QKV GEMM: Opart (8.4M) @0, ml (.5M) @8.4M, ab (4M) @9M
// ---------------------------------------------------------------------------
extern "C" void kernel_launch(void* const* d_in, const int* in_sizes, int n_in,
                              void* d_out, int out_size, void* d_ws, size_t ws_size,
                              hipStream_t stream) {
    (void)in_sizes; (void)n_in; (void)out_size; (void)ws_size;
    const float* hs = (const float*)d_in[0];
    const float* Wq = (const float*)d_in[1];
    const float* Wk = (const float*)d_in[2];
    const float* Wv = (const float*)d_in[3];
    const float* Wo = (const float*)d_in[4];
    const float* rb = (const float*)d_in[5];

    char* p = (char*)d_ws;
    half_t* Wqkv = (half_t*)p;            p += 768 * 1024 * 2;
    half_t* Wo_e = (half_t*)p;            p += 1024 * 256 * 2;
    float*  btab = (float*)p;             p += 4 * 4096 * 4;
    char*   hshp = p;                     p += (size_t)8192 * 1024 * 2;
    half_t* qkv  = (half_t*)p;            p += (size_t)8192 * 768 * 2;
    half_t* vt   = (half_t*)p;            p += (size_t)16 * 64 * 2048 * 2;
    half_t* hsh   = (half_t*)hshp;
    half_t* Opart = (half_t*)hshp;                               // 8.4 MB
    float*  mlbuf = (float*)(hshp + (size_t)1024 * 64 * 64 * 2); // 0.5 MB
    half_t* ab    = (half_t*)(hshp + (size_t)9 * 1024 * 1024);   // 4 MB
    float*  out  = (float*)d_out;

    // fused cvt (blocks 0..4095) + weight/bias prep (blocks 4096..7167)
    prep<<<7168, 256, 0, stream>>>(hs, Wq, Wk, Wv, Wo, rb, hsh, Wqkv, Wo_e, btab);

    // qkv[8192,768] = hsh * Wqkv^T; V column-blocks go straight to vt (fused
    // transpose + token permutation). 128x128 tiles (2x MFMA density):
    // grid 6x64 = 384 blocks, 2 blocks/CU capacity (all co-resident).
    gemm_nt_mfma<128><<<6 * 64, 256, 0, stream>>>(hsh, Wqkv, qkv, 768, 1024, 1, vt);

    // split-K=2 flash attention (1024 blocks, 4/CU, XCD group clustering)
    attn<<<1024, 256, 0, stream>>>(qkv, vt, btab, Opart, mlbuf);
    merge<<<512, 256, 0, stream>>>(Opart, mlbuf, ab);

    // out[8192,1024] = ab[8192,256] * Wo_e[1024,256]^T; 128x128 tiles,
    // grid 8x64 = 512 blocks = 2/CU balanced.
    gemm_nt_mfma<128><<<8 * 64, 256, 0, stream>>>(ab, Wo_e, out, 1024, 256, 0, nullptr);
}

// Round 11
// 166.658 us; speedup vs baseline: 1.0041x; 1.0041x over previous
//
#include <hip/hip_runtime.h>
#include <math.h>

typedef _Float16 half_t;
typedef _Float16 half4 __attribute__((ext_vector_type(4)));
typedef _Float16 half8 __attribute__((ext_vector_type(8)));
typedef float f32x4 __attribute__((ext_vector_type(4)));

#define LOG2E 1.44269504088896f

// async global -> LDS, 16 B per lane; lds base wave-uniform, lane i at base+i*16.
__device__ __forceinline__ void gload16(const void* g, void* l) {
    __builtin_amdgcn_global_load_lds(
        (const __attribute__((address_space(1))) unsigned int*)g,
        (__attribute__((address_space(3))) unsigned int*)l, 16, 0, 0);
}

// raw v_exp_f32 (inputs are max-shifted <= 0; denorm-flush is harmless here)
__device__ __forceinline__ float fast_exp2(float x) {
    return __builtin_amdgcn_exp2f(x);
}

// ---------------------------------------------------------------------------
// prep (fused): blocks 0..4095 convert hs fp32->fp16; blocks 4096.. build
// group-reduced effective weights (fp16) + log2-domain bias table (fp32).
// ---------------------------------------------------------------------------
__global__ __launch_bounds__(256) void prep(const float* __restrict__ hs,
                     const float* __restrict__ Wq, const float* __restrict__ Wk,
                     const float* __restrict__ Wv, const float* __restrict__ Wo,
                     const float* __restrict__ rb,
                     half_t* __restrict__ hsh,
                     half_t* __restrict__ Wqkv, half_t* __restrict__ Wo_e,
                     float* __restrict__ btab) {
    if (blockIdx.x < 4096) {
        int i = (blockIdx.x * 256 + threadIdx.x) * 8;
        f32x4 a = *(const f32x4*)&hs[i];
        f32x4 b = *(const f32x4*)&hs[i + 4];
        half8 o;
        #pragma unroll
        for (int j = 0; j < 4; ++j) { o[j] = (half_t)a[j]; o[4 + j] = (half_t)b[j]; }
        *(half8*)&hsh[i] = o;
        return;
    }
    int idx = (blockIdx.x - 4096) * 256 + threadIdx.x;
    if (idx < 768 * 1024) {
        int row = idx >> 10, col = idx & 1023;
        int sec = row >> 8;
        int r = row & 255;
        int h = r >> 6, d = r & 63;
        const float* W = (sec == 0) ? Wq : ((sec == 1) ? Wk : Wv);
        float s = 0.f;
        #pragma unroll
        for (int g = 0; g < 4; ++g) s += W[((g * 4 + h) * 64 + d) * 1024 + col];
        s *= (sec == 0) ? LOG2E : 0.25f;   // fold log2e into q-projection
        Wqkv[idx] = (half_t)s;
    }
    if (idx < 1024 * 256) {
        int m = idx >> 8, c = idx & 255;
        float s = 0.f;
        #pragma unroll
        for (int g = 0; g < 4; ++g) s += Wo[m * 1024 + g * 256 + c];
        Wo_e[idx] = (half_t)s;
    }
    if (idx < 4 * 4096) {
        int h = idx >> 12, dpos = idx & 4095;
        int delta = dpos - 2048;
        int bucket = (delta > 0) ? 16 : 0;
        int ad = delta < 0 ? -delta : delta;
        if (ad < 8) bucket += ad;
        else {
            int large = 8 + (int)(logf((float)ad * 0.125f) / logf(16.0f) * 8.0f);
            bucket += (large < 15) ? large : 15;
        }
        float s = 0.f;
        #pragma unroll
        for (int g = 0; g < 4; ++g) s += rb[bucket * 16 + g * 4 + h];
        btab[idx] = s * 0.25f * LOG2E;     // log2-domain bias
    }
}

// ---------------------------------------------------------------------------
// MFMA NT GEMM: C[M,N] = A[M,K]*B[N,K]^T, fp16 in. 128xBN tile, 4 waves of
// 64x(BN/2), BK=64. Double-buffered LDS, single barrier + vmcnt(0) per
// K-step, prefetch issued before compute.
// BN=64: LDS 48KB -> 3 blocks/CU (best for gemm1, K=1024 — measured R10).
// BN=128: LDS 64KB -> 2 blocks/CU (gemm2, K=256).
// 1D grid, y-panel XCD clustering: rowBase = (flat & 63)*128.
// If vtp != null and colBase >= 512 (the V column range), the result is
// written TRANSPOSED to vt[(b*4+h)*64+d][n'] (fuses transpose_v), with the
// token index PERMUTED within each 64-token tile: t[5:4] <-> t[3:2]
// (involution). This makes attn's PV LDS reads conflict-free b128s.
// ---------------------------------------------------------------------------
template <int BN>
__global__ __launch_bounds__(256) void gemm_nt_mfma(const half_t* __restrict__ A,
                                                    const half_t* __restrict__ B,
                                                    void* __restrict__ Cptr,
                                                    int N, int K, int store_half,
                                                    half_t* __restrict__ vtp) {
    constexpr int JN = BN / 32;               // col frags per wave
    __shared__ __attribute__((aligned(16))) half_t As[2][128 * 64];
    __shared__ __attribute__((aligned(16))) half_t Bs[2][BN * 64];
    int tid = threadIdx.x;
    int w = tid >> 6, lane = tid & 63;
    int c = lane & 15, quad = lane >> 4;
    int flat = blockIdx.x;
    int rowBase = (flat & 63) * 128;          // same A-panel -> same XCD
    int colBase = (flat >> 6) * BN;
    int wr = (w & 1) * 64, wc = (w >> 1) * (16 * JN);

    f32x4 acc[4][JN];
    #pragma unroll
    for (int i = 0; i < 4; ++i)
        #pragma unroll
        for (int j = 0; j < JN; ++j) acc[i][j] = (f32x4)(0.f);

    int srow = tid >> 3;                          // 0..31
    int kcs = ((tid & 7) ^ (srow & 7)) * 8;       // swizzled source k-chunk
    int rx = c & 7;
    int nsteps = K >> 6;

    auto stage = [&](int ks) {
        int bb = ks & 1;
        #pragma unroll
        for (int p = 0; p < 4; ++p)
            gload16(&A[(size_t)(rowBase + srow + 32 * p) * K + ks * 64 + kcs],
                    &As[bb][p * 2048 + w * 512]);
        #pragma unroll
        for (int p = 0; p < BN / 32; ++p)
            gload16(&B[(size_t)(colBase + srow + 32 * p) * K + ks * 64 + kcs],
                    &Bs[bb][p * 2048 + w * 512]);
    };

    stage(0);
    __syncthreads();

    for (int ks = 0; ks < nsteps; ++ks) {
        if (ks + 1 < nsteps) stage(ks + 1);       // prefetch into other buffer
        const half_t* Ab = As[ks & 1];
        const half_t* Bb = Bs[ks & 1];
        __builtin_amdgcn_s_setprio(1);
        #pragma unroll
        for (int kh = 0; kh < 2; ++kh) {
            int xk = ((quad + 4 * kh) ^ rx) * 8;
            half8 af[4], bf[JN];
            #pragma unroll
            for (int i = 0; i < 4; ++i)
                af[i] = *(const half8*)&Ab[(wr + i * 16 + c) * 64 + xk];
            #pragma unroll
            for (int j = 0; j < JN; ++j)
                bf[j] = *(const half8*)&Bb[(wc + j * 16 + c) * 64 + xk];
            #pragma unroll
            for (int i = 0; i < 4; ++i)
                #pragma unroll
                for (int j = 0; j < JN; ++j)
                    acc[i][j] = __builtin_amdgcn_mfma_f32_16x16x32_f16(af[i], bf[j], acc[i][j], 0, 0, 0);
        }
        __builtin_amdgcn_s_setprio(0);
        __asm__ __volatile__("s_waitcnt vmcnt(0)" ::: "memory");
        __builtin_amdgcn_s_barrier();
    }

    if (vtp && colBase >= 512) {
        #pragma unroll
        for (int i = 0; i < 4; ++i)
            #pragma unroll
            for (int j = 0; j < JN; ++j) {
                int row0 = rowBase + wr + i * 16 + quad * 4;   // 4 consecutive tokens
                int vcol = colBase - 512 + wc + j * 16 + c;
                int hh = vcol >> 6, dd = vcol & 63;
                int b = row0 >> 11, n0 = row0 & 2047;
                int t = n0 & 63;                               // multiple of 4
                int np = (n0 & ~63) | (((t >> 2) & 3) << 4) | (((t >> 4) & 3) << 2);
                half4 pk;
                #pragma unroll
                for (int reg = 0; reg < 4; ++reg) pk[reg] = (half_t)acc[i][j][reg];
                *(half4*)&vtp[((size_t)((b * 4 + hh) * 64 + dd)) * 2048 + np] = pk;
            }
        return;
    }

    #pragma unroll
    for (int i = 0; i < 4; ++i)
        #pragma unroll
        for (int j = 0; j < JN; ++j)
            #pragma unroll
            for (int reg = 0; reg < 4; ++reg) {
                size_t row = rowBase + wr + i * 16 + quad * 4 + reg;
                size_t col = colBase + wc + j * 16 + c;
                if (store_half) ((half_t*)Cptr)[row * N + col] = (half_t)acc[i][j][reg];
                else            ((float*)Cptr)[row * N + col] = acc[i][j][reg];
            }
}

// ---------------------------------------------------------------------------
// Split-K flash attention, S^T + O^T, per-lane online softmax, register-P
// (PV via mfma_f32_16x16x16_f16, B-operand = exp'd S^T chunk in-lane).
// R7 structure exactly (best measured: 42.9 us / total 164.6):
//  * V tiles stored token-PERMUTED (t[5:4]<->t[3:2], written by the QKV GEMM)
//    -> PV reads are 2 x ds_read_b128 per db (2-way banks = free).
//  * Split counted-vmcnt (T4): stage issues K loads then V loads; mid-iter
//    vmcnt(4)+barrier gates PV on old V only; bottom vmcnt(2)+barrier gates
//    next QK on K only (V stays in flight). No exposed latency.
// K/V double-buffered, LDS = 32768 B -> 4 blocks/CU.
// 1D grid with XCD group clustering: g = flat & 31 encodes (h, b, s).
//  S^T = K Q^T -> D[key, q=c];  O^T = V^T P^T -> D[d, q=c].
// ---------------------------------------------------------------------------
__global__ __launch_bounds__(256) void attn(const half_t* __restrict__ qkv,
                                            const half_t* __restrict__ vt,
                                            const float* __restrict__ btab,
                                            half_t* __restrict__ Opart,
                                            float* __restrict__ ml) {
    __shared__ __attribute__((aligned(16))) half_t Ks[2][64 * 64];
    __shared__ __attribute__((aligned(16))) half_t Vts[2][64 * 64];

    int tid = threadIdx.x;
    int w = tid >> 6, lane = tid & 63;
    int c = lane & 15, quad = lane >> 4;
    int flat = blockIdx.x;
    int g = flat & 31;                 // group id: same group -> same XCD
    int qt = flat >> 5;
    int h = g & 3;
    int zz = g >> 2;
    int b = zz >> 1, s = zz & 1;
    int q0 = qt * 64;
    int bh = b * 4 + h;
    int k0g = s * 1024;

    // Q fragments (B-operand: n=q=c, k=quad*8+j), pre-scaled by log2e
    const half_t* qrow = qkv + (size_t)(b * 2048 + q0 + w * 16 + c) * 768 + h * 64;
    half8 qf0 = *(const half8*)(qrow + quad * 8);
    half8 qf1 = *(const half8*)(qrow + 32 + quad * 8);

    // far-field bias constants (bucket saturates for |delta|>=128)
    float cpos = btab[h * 4096 + 4095];
    float cneg = btab[h * 4096];

    // near-tile bias base: btab[h][ (k - q) + 2048 ], k = ktg + koff
    const float* bpt = btab + h * 4096 + 2048 + k0g - (q0 + w * 16 + c);

    // staging: srow = tid>>3 (0..31, +32 on 2nd instr), chunk tid&7,
    // source chunk xor-swizzled by row&7.
    int srow = tid >> 3;
    int kcs = ((tid & 7) ^ (srow & 7)) * 8;
    const half_t* gK = qkv + (size_t)(b * 2048 + k0g + srow) * 768 + 256 + h * 64 + kcs;
    const half_t* gV = vt + (size_t)(bh * 64 + srow) * 2048 + k0g + kcs;

    // issue order matters: K loads first (bottom vmcnt(2) leaves V in flight)
    auto stage = [&](int it2) {
        int bb = it2 & 1;
        const half_t* gKt = gK + (size_t)(it2 * 64) * 768;
        const half_t* gVt = gV + it2 * 64;
        gload16(gKt,                     &Ks[bb][w * 512]);
        gload16(gKt + (size_t)32 * 768,  &Ks[bb][2048 + w * 512]);
        gload16(gVt,                     &Vts[bb][w * 512]);
        gload16(gVt + 32 * 2048,         &Vts[bb][2048 + w * 512]);
    };

    f32x4 O[4];
    #pragma unroll
    for (int i = 0; i < 4; ++i) O[i] = (f32x4)(0.f);
    float mrow = -1e30f, lrow = 0.f;

    int rx = c & 7;

    // prologue: tile 0 staged, full drain once.
    stage(0);
    __syncthreads();

    for (int it = 0; it < 16; ++it) {
        int ktg = k0g + it * 64;
        if (it < 15) stage(it + 1);               // prefetch into other buffer
        const half_t* Kb = Ks[it & 1];
        const half_t* Vb = Vts[it & 1];

        // S^T = K Q^T : D[key = kb*16 + quad*4+rg, q = c]
        f32x4 ST[4];
        __builtin_amdgcn_s_setprio(1);
        #pragma unroll
        for (int kb = 0; kb < 4; ++kb) {
            int row = kb * 16 + c;
            half8 kf0 = *(const half8*)&Kb[row * 64 + (quad ^ rx) * 8];
            half8 kf1 = *(const half8*)&Kb[row * 64 + ((quad + 4) ^ rx) * 8];
            f32x4 a = (f32x4)(0.f);
            a = __builtin_amdgcn_mfma_f32_16x16x32_f16(kf0, qf0, a, 0, 0, 0);
            a = __builtin_amdgcn_mfma_f32_16x16x32_f16(kf1, qf1, a, 0, 0, 0);
            ST[kb] = a;
        }
        __builtin_amdgcn_s_setprio(0);

        // bias: near tiles gather from btab (L2-resident); far tiles fold
        // the saturated constant cb into madj.
        float cb;
        if (ktg >= q0 + 191) {
            cb = cpos;
        } else if (ktg + 191 <= q0) {
            cb = cneg;
        } else {
            cb = 0.f;
            const float* bp = bpt + it * 64;
            #pragma unroll
            for (int kb = 0; kb < 4; ++kb)
                #pragma unroll
                for (int rg = 0; rg < 4; ++rg)
                    ST[kb][rg] += bp[kb * 16 + quad * 4 + rg];
        }

        // tile max: in-lane 16 keys + 2 swizzles (lanes sharing q = c)
        float tmax = -1e30f;
        #pragma unroll
        for (int kb = 0; kb < 4; ++kb)
            #pragma unroll
            for (int rg = 0; rg < 4; ++rg) tmax = fmaxf(tmax, ST[kb][rg]);
        tmax += cb;
        tmax = fmaxf(tmax, __shfl_xor(tmax, 16));
        tmax = fmaxf(tmax, __shfl_xor(tmax, 32));

        float mnew = fmaxf(mrow, tmax);
        float alpha = fast_exp2(mrow - mnew);     // per-lane scalar
        mrow = mnew;
        float madj = mnew - cb;

        // p = exp2(S - madj) (max-shifted: fp16-safe), kept IN REGISTERS:
        // pc[kb] is directly the B-operand of PV MFMA #kb (k=quad*4+i, col=c).
        half4 pc[4];
        float lsum = 0.f;
        #pragma unroll
        for (int kb = 0; kb < 4; ++kb) {
            #pragma unroll
            for (int rg = 0; rg < 4; ++rg) {
                float p = fast_exp2(ST[kb][rg] - madj);
                lsum += p;
                pc[kb][rg] = (half_t)p;
            }
        }
        lrow = lrow * alpha + lsum;               // in-lane (shared m)

        // mid sync: own old-V done (4 new loads stay in flight), then all waves
        if (it < 15) { __asm__ __volatile__("s_waitcnt vmcnt(4)" ::: "memory"); }
        else         { __asm__ __volatile__("s_waitcnt vmcnt(0)" ::: "memory"); }
        __builtin_amdgcn_s_barrier();

        // O^T[d, q=c] += V^T P^T via 16x16x16 MFMA. V tile is token-permuted
        // (p = quad*16 + kb*4 + i holds original k = kb*16 + quad*4 + i), so
        // each lane's 16 needed halfs are 2 b128 reads (chunks 2q^rx, 2q+1^rx).
        __builtin_amdgcn_s_setprio(1);
        #pragma unroll
        for (int db = 0; db < 4; ++db) {
            const half_t* vrow = &Vb[(db * 16 + c) * 64];
            half8 v01 = *(const half8*)&vrow[((quad * 2) ^ rx) * 8];       // kb=0,1
            half8 v23 = *(const half8*)&vrow[((quad * 2 + 1) ^ rx) * 8];   // kb=2,3
            f32x4 o = O[db];
            #pragma unroll
            for (int rg = 0; rg < 4; ++rg) o[rg] *= alpha;      // per-lane alpha
            o = __builtin_amdgcn_mfma_f32_16x16x16f16(
                    __builtin_shufflevector(v01, v01, 0, 1, 2, 3), pc[0], o, 0, 0, 0);
            o = __builtin_amdgcn_mfma_f32_16x16x16f16(
                    __builtin_shufflevector(v01, v01, 4, 5, 6, 7), pc[1], o, 0, 0, 0);
            o = __builtin_amdgcn_mfma_f32_16x16x16f16(
                    __builtin_shufflevector(v23, v23, 0, 1, 2, 3), pc[2], o, 0, 0, 0);
            o = __builtin_amdgcn_mfma_f32_16x16x16f16(
                    __builtin_shufflevector(v23, v23, 4, 5, 6, 7), pc[3], o, 0, 0, 0);
            O[db] = o;
        }
        __builtin_amdgcn_s_setprio(0);

        // bottom sync: own K(it+1) done (V(it+1) stays in flight), then all waves
        if (it < 15) {
            __asm__ __volatile__("s_waitcnt vmcnt(2)" ::: "memory");
            __builtin_amdgcn_s_barrier();
        }
    }

    // total l across the 4 quad-lanes (same final m), normalize, store
    lrow += __shfl_xor(lrow, 16);
    lrow += __shfl_xor(lrow, 32);
    float inv = 1.0f / lrow;

    int pb = (bh * 32 + qt) * 2 + s;
    #pragma unroll
    for (int db = 0; db < 4; ++db) {
        half4 pk;
        #pragma unroll
        for (int rg = 0; rg < 4; ++rg) pk[rg] = (half_t)(O[db][rg] * inv);
        *(half4*)&Opart[((size_t)pb * 64 + w * 16 + c) * 64 + db * 16 + quad * 4] = pk;
    }
    if (quad == 0) {
        ml[pb * 128 + w * 16 + c] = mrow;
        ml[pb * 128 + 64 + w * 16 + c] = lrow;
    }
}

// ---------------------------------------------------------------------------
// merge the two split-K partials -> ab[b*2048+n][h*64+d]
// Partials normalized: out = (w1*O1 + w2*O2), w_i = 2^(m_i-m) * l_i / Z.
// ---------------------------------------------------------------------------
__global__ __launch_bounds__(256) void merge(const half_t* __restrict__ Opart,
                                             const float* __restrict__ ml,
                                             half_t* __restrict__ ab) {
    int bq = blockIdx.x;            // bh*32 + qt
    int bh = bq >> 5, qt = bq & 31;
    int b = bh >> 2, h = bh & 3;
    int row = threadIdx.x >> 2;
    int cg = (threadIdx.x & 3) * 16;
    int p0 = bq * 2, p1 = p0 + 1;
    float m1 = ml[p0 * 128 + row], l1 = ml[p0 * 128 + 64 + row];
    float m2 = ml[p1 * 128 + row], l2 = ml[p1 * 128 + 64 + row];
    float m = fmaxf(m1, m2);
    float a1 = __builtin_amdgcn_exp2f(m1 - m) * l1;
    float a2 = __builtin_amdgcn_exp2f(m2 - m) * l2;
    float inv = 1.f / (a1 + a2);
    float w1 = a1 * inv, w2 = a2 * inv;
    const half8* o1 = (const half8*)&Opart[((size_t)p0 * 64 + row) * 64 + cg];
    const half8* o2 = (const half8*)&Opart[((size_t)p1 * 64 + row) * 64 + cg];
    half_t* dst = ab + (size_t)(b * 2048 + qt * 64 + row) * 256 + h * 64 + cg;
    #pragma unroll
    for (int v = 0; v < 2; ++v) {
        half8 x = o1[v], y = o2[v], o;
        #pragma unroll
        for (int j = 0; j < 8; ++j)
            o[j] = (half_t)((float)x[j] * w1 + (float)y[j] * w2);
        *(half8*)(dst + v * 8) = o;
    }
}

// ---------------------------------------------------------------------------
// Launch. ws: Wqkv 1.5M | Wo_e .5M | btab 64K | hsh 16M | qkv 12M | vt 4M
// hsh region reused after QKV GEMM: Opart (8.4M) @0, ml (.5M) @8.4M, ab (4M) @9M
// ---------------------------------------------------------------------------
extern "C" void kernel_launch(void* const* d_in, const int* in_sizes, int n_in,
                              void* d_out, int out_size, void* d_ws, size_t ws_size,
                              hipStream_t stream) {
    (void)in_sizes; (void)n_in; (void)out_size; (void)ws_size;
    const float* hs = (const float*)d_in[0];
    const float* Wq = (const float*)d_in[1];
    const float* Wk = (const float*)d_in[2];
    const float* Wv = (const float*)d_in[3];
    const float* Wo = (const float*)d_in[4];
    const float* rb = (const float*)d_in[5];

    char* p = (char*)d_ws;
    half_t* Wqkv = (half_t*)p;            p += 768 * 1024 * 2;
    half_t* Wo_e = (half_t*)p;            p += 1024 * 256 * 2;
    float*  btab = (float*)p;             p += 4 * 4096 * 4;
    char*   hshp = p;                     p += (size_t)8192 * 1024 * 2;
    half_t* qkv  = (half_t*)p;            p += (size_t)8192 * 768 * 2;
    half_t* vt   = (half_t*)p;            p += (size_t)16 * 64 * 2048 * 2;
    half_t* hsh   = (half_t*)hshp;
    half_t* Opart = (half_t*)hshp;                               // 8.4 MB
    float*  mlbuf = (float*)(hshp + (size_t)1024 * 64 * 64 * 2); // 0.5 MB
    half_t* ab    = (half_t*)(hshp + (size_t)9 * 1024 * 1024);   // 4 MB
    float*  out  = (float*)d_out;

    // fused cvt (blocks 0..4095) + weight/bias prep (blocks 4096..7167)
    prep<<<7168, 256, 0, stream>>>(hs, Wq, Wk, Wv, Wo, rb, hsh, Wqkv, Wo_e, btab);

    // qkv[8192,768] = hsh * Wqkv^T; V column-blocks go straight to vt (fused
    // transpose + token permutation). 128x64 tiles: 768 blocks = 3/CU
    // (measured best vs BN=128's 2/CU — R10 A/B).
    gemm_nt_mfma<64><<<12 * 64, 256, 0, stream>>>(hsh, Wqkv, qkv, 768, 1024, 1, vt);

    // split-K=2 flash attention (1024 blocks, 4/CU, XCD group clustering)
    attn<<<1024, 256, 0, stream>>>(qkv, vt, btab, Opart, mlbuf);
    merge<<<512, 256, 0, stream>>>(Opart, mlbuf, ab);

    // out[8192,1024] = ab[8192,256] * Wo_e[1024,256]^T; 128x128 tiles,
    // grid 8x64 = 512 blocks = 2/CU balanced.
    gemm_nt_mfma<128><<<8 * 64, 256, 0, stream>>>(ab, Wo_e, out, 1024, 256, 0, nullptr);
}

// Round 12
// 162.233 us; speedup vs baseline: 1.0315x; 1.0273x over previous
//
#include <hip/hip_runtime.h>
#include <math.h>

typedef _Float16 half_t;
typedef _Float16 half4 __attribute__((ext_vector_type(4)));
typedef _Float16 half8 __attribute__((ext_vector_type(8)));
typedef float f32x4 __attribute__((ext_vector_type(4)));

#define LOG2E 1.44269504088896f

// async global -> LDS, 16 B per lane; lds base wave-uniform, lane i at base+i*16.
__device__ __forceinline__ void gload16(const void* g, void* l) {
    __builtin_amdgcn_global_load_lds(
        (const __attribute__((address_space(1))) unsigned int*)g,
        (__attribute__((address_space(3))) unsigned int*)l, 16, 0, 0);
}

// raw v_exp_f32 (inputs are max-shifted <= 0; denorm-flush is harmless here)
__device__ __forceinline__ float fast_exp2(float x) {
    return __builtin_amdgcn_exp2f(x);
}

// ---------------------------------------------------------------------------
// prep (fused): blocks 0..4095 convert hs fp32->fp16; blocks 4096.. build
// group-reduced effective weights (fp16) + log2-domain bias table (fp32).
// ---------------------------------------------------------------------------
__global__ __launch_bounds__(256) void prep(const float* __restrict__ hs,
                     const float* __restrict__ Wq, const float* __restrict__ Wk,
                     const float* __restrict__ Wv, const float* __restrict__ Wo,
                     const float* __restrict__ rb,
                     half_t* __restrict__ hsh,
                     half_t* __restrict__ Wqkv, half_t* __restrict__ Wo_e,
                     float* __restrict__ btab) {
    if (blockIdx.x < 4096) {
        int i = (blockIdx.x * 256 + threadIdx.x) * 8;
        f32x4 a = *(const f32x4*)&hs[i];
        f32x4 b = *(const f32x4*)&hs[i + 4];
        half8 o;
        #pragma unroll
        for (int j = 0; j < 4; ++j) { o[j] = (half_t)a[j]; o[4 + j] = (half_t)b[j]; }
        *(half8*)&hsh[i] = o;
        return;
    }
    int idx = (blockIdx.x - 4096) * 256 + threadIdx.x;
    if (idx < 768 * 1024) {
        int row = idx >> 10, col = idx & 1023;
        int sec = row >> 8;
        int r = row & 255;
        int h = r >> 6, d = r & 63;
        const float* W = (sec == 0) ? Wq : ((sec == 1) ? Wk : Wv);
        float s = 0.f;
        #pragma unroll
        for (int g = 0; g < 4; ++g) s += W[((g * 4 + h) * 64 + d) * 1024 + col];
        s *= (sec == 0) ? LOG2E : 0.25f;   // fold log2e into q-projection
        Wqkv[idx] = (half_t)s;
    }
    if (idx < 1024 * 256) {
        int m = idx >> 8, c = idx & 255;
        float s = 0.f;
        #pragma unroll
        for (int g = 0; g < 4; ++g) s += Wo[m * 1024 + g * 256 + c];
        Wo_e[idx] = (half_t)s;
    }
    if (idx < 4 * 4096) {
        int h = idx >> 12, dpos = idx & 4095;
        int delta = dpos - 2048;
        int bucket = (delta > 0) ? 16 : 0;
        int ad = delta < 0 ? -delta : delta;
        if (ad < 8) bucket += ad;
        else {
            int large = 8 + (int)(logf((float)ad * 0.125f) / logf(16.0f) * 8.0f);
            bucket += (large < 15) ? large : 15;
        }
        float s = 0.f;
        #pragma unroll
        for (int g = 0; g < 4; ++g) s += rb[bucket * 16 + g * 4 + h];
        btab[idx] = s * 0.25f * LOG2E;     // log2-domain bias
    }
}

// ---------------------------------------------------------------------------
// MFMA NT GEMM: C[M,N] = A[M,K]*B[N,K]^T, fp16 in. 128xBN tile, 4 waves of
// 64x(BN/2), BK=64. Double-buffered LDS, single barrier + vmcnt(0) per
// K-step, prefetch issued before compute.
// BN=64: LDS 48KB -> 3 blocks/CU (best for gemm1, K=1024 — measured R10);
//        launch_bounds min-waves 3 -> VGPR cap ~170 (no starvation).
// BN=128: LDS 64KB -> 2 blocks/CU (gemm2); min-waves 2 -> VGPR cap 256.
// 1D grid, y-panel XCD clustering: rowBase = (flat & 63)*128.
// If vtp != null and colBase >= 512 (the V column range), the result is
// written TRANSPOSED to vt[(b*4+h)*64+d][n'] (fuses transpose_v), with the
// token index PERMUTED within each 64-token tile: t[5:4] <-> t[3:2]
// (involution). This makes attn's PV LDS reads conflict-free b128s.
// ---------------------------------------------------------------------------
template <int BN>
__global__ __launch_bounds__(256, (BN == 64 ? 3 : 2)) void gemm_nt_mfma(
                                                    const half_t* __restrict__ A,
                                                    const half_t* __restrict__ B,
                                                    void* __restrict__ Cptr,
                                                    int N, int K, int store_half,
                                                    half_t* __restrict__ vtp) {
    constexpr int JN = BN / 32;               // col frags per wave
    __shared__ __attribute__((aligned(16))) half_t As[2][128 * 64];
    __shared__ __attribute__((aligned(16))) half_t Bs[2][BN * 64];
    int tid = threadIdx.x;
    int w = tid >> 6, lane = tid & 63;
    int c = lane & 15, quad = lane >> 4;
    int flat = blockIdx.x;
    int rowBase = (flat & 63) * 128;          // same A-panel -> same XCD
    int colBase = (flat >> 6) * BN;
    int wr = (w & 1) * 64, wc = (w >> 1) * (16 * JN);

    f32x4 acc[4][JN];
    #pragma unroll
    for (int i = 0; i < 4; ++i)
        #pragma unroll
        for (int j = 0; j < JN; ++j) acc[i][j] = (f32x4)(0.f);

    int srow = tid >> 3;                          // 0..31
    int kcs = ((tid & 7) ^ (srow & 7)) * 8;       // swizzled source k-chunk
    int rx = c & 7;
    int nsteps = K >> 6;

    auto stage = [&](int ks) {
        int bb = ks & 1;
        #pragma unroll
        for (int p = 0; p < 4; ++p)
            gload16(&A[(size_t)(rowBase + srow + 32 * p) * K + ks * 64 + kcs],
                    &As[bb][p * 2048 + w * 512]);
        #pragma unroll
        for (int p = 0; p < BN / 32; ++p)
            gload16(&B[(size_t)(colBase + srow + 32 * p) * K + ks * 64 + kcs],
                    &Bs[bb][p * 2048 + w * 512]);
    };

    stage(0);
    __syncthreads();

    for (int ks = 0; ks < nsteps; ++ks) {
        if (ks + 1 < nsteps) stage(ks + 1);       // prefetch into other buffer
        const half_t* Ab = As[ks & 1];
        const half_t* Bb = Bs[ks & 1];
        __builtin_amdgcn_s_setprio(1);
        #pragma unroll
        for (int kh = 0; kh < 2; ++kh) {
            int xk = ((quad + 4 * kh) ^ rx) * 8;
            half8 af[4], bf[JN];
            #pragma unroll
            for (int i = 0; i < 4; ++i)
                af[i] = *(const half8*)&Ab[(wr + i * 16 + c) * 64 + xk];
            #pragma unroll
            for (int j = 0; j < JN; ++j)
                bf[j] = *(const half8*)&Bb[(wc + j * 16 + c) * 64 + xk];
            #pragma unroll
            for (int i = 0; i < 4; ++i)
                #pragma unroll
                for (int j = 0; j < JN; ++j)
                    acc[i][j] = __builtin_amdgcn_mfma_f32_16x16x32_f16(af[i], bf[j], acc[i][j], 0, 0, 0);
        }
        __builtin_amdgcn_s_setprio(0);
        __asm__ __volatile__("s_waitcnt vmcnt(0)" ::: "memory");
        __builtin_amdgcn_s_barrier();
    }

    if (vtp && colBase >= 512) {
        #pragma unroll
        for (int i = 0; i < 4; ++i)
            #pragma unroll
            for (int j = 0; j < JN; ++j) {
                int row0 = rowBase + wr + i * 16 + quad * 4;   // 4 consecutive tokens
                int vcol = colBase - 512 + wc + j * 16 + c;
                int hh = vcol >> 6, dd = vcol & 63;
                int b = row0 >> 11, n0 = row0 & 2047;
                int t = n0 & 63;                               // multiple of 4
                int np = (n0 & ~63) | (((t >> 2) & 3) << 4) | (((t >> 4) & 3) << 2);
                half4 pk;
                #pragma unroll
                for (int reg = 0; reg < 4; ++reg) pk[reg] = (half_t)acc[i][j][reg];
                *(half4*)&vtp[((size_t)((b * 4 + hh) * 64 + dd)) * 2048 + np] = pk;
            }
        return;
    }

    #pragma unroll
    for (int i = 0; i < 4; ++i)
        #pragma unroll
        for (int j = 0; j < JN; ++j)
            #pragma unroll
            for (int reg = 0; reg < 4; ++reg) {
                size_t row = rowBase + wr + i * 16 + quad * 4 + reg;
                size_t col = colBase + wc + j * 16 + c;
                if (store_half) ((half_t*)Cptr)[row * N + col] = (half_t)acc[i][j][reg];
                else            ((float*)Cptr)[row * N + col] = acc[i][j][reg];
            }
}

// ---------------------------------------------------------------------------
// Split-K flash attention, S^T + O^T, per-lane online softmax, register-P
// (PV via mfma_f32_16x16x16_f16, B-operand = exp'd S^T chunk in-lane).
// R7 structure exactly (best measured: 42.9 us / total 164.6), plus
// __launch_bounds__(256, 4): grid caps occupancy at 4 blocks/CU = 4
// waves/SIMD anyway, so cap VGPR at 128 instead of the allocator's
// self-imposed 52 — lets Q fragments / base pointers / addressing
// invariants stay resident across the asm-"memory" barriers instead of
// being rematerialized every iteration (the suspected hidden ~60
// VALU instr/iter).
//  * V tiles stored token-PERMUTED (t[5:4]<->t[3:2], written by the QKV GEMM)
//    -> PV reads are 2 x ds_read_b128 per db (2-way banks = free).
//  * Split counted-vmcnt (T4): stage issues K loads then V loads; mid-iter
//    vmcnt(4)+barrier gates PV on old V only; bottom vmcnt(2)+barrier gates
//    next QK on K only (V stays in flight). No exposed latency.
// K/V double-buffered, LDS = 32768 B -> 4 blocks/CU.
// 1D grid with XCD group clustering: g = flat & 31 encodes (h, b, s).
//  S^T = K Q^T -> D[key, q=c];  O^T = V^T P^T -> D[d, q=c].
// ---------------------------------------------------------------------------
__global__ __launch_bounds__(256, 4) void attn(const half_t* __restrict__ qkv,
                                            const half_t* __restrict__ vt,
                                            const float* __restrict__ btab,
                                            half_t* __restrict__ Opart,
                                            float* __restrict__ ml) {
    __shared__ __attribute__((aligned(16))) half_t Ks[2][64 * 64];
    __shared__ __attribute__((aligned(16))) half_t Vts[2][64 * 64];

    int tid = threadIdx.x;
    int w = tid >> 6, lane = tid & 63;
    int c = lane & 15, quad = lane >> 4;
    int flat = blockIdx.x;
    int g = flat & 31;                 // group id: same group -> same XCD
    int qt = flat >> 5;
    int h = g & 3;
    int zz = g >> 2;
    int b = zz >> 1, s = zz & 1;
    int q0 = qt * 64;
    int bh = b * 4 + h;
    int k0g = s * 1024;

    // Q fragments (B-operand: n=q=c, k=quad*8+j), pre-scaled by log2e
    const half_t* qrow = qkv + (size_t)(b * 2048 + q0 + w * 16 + c) * 768 + h * 64;
    half8 qf0 = *(const half8*)(qrow + quad * 8);
    half8 qf1 = *(const half8*)(qrow + 32 + quad * 8);

    // far-field bias constants (bucket saturates for |delta|>=128)
    float cpos = btab[h * 4096 + 4095];
    float cneg = btab[h * 4096];

    // near-tile bias base: btab[h][ (k - q) + 2048 ], k = ktg + koff
    const float* bpt = btab + h * 4096 + 2048 + k0g - (q0 + w * 16 + c);

    // staging: srow = tid>>3 (0..31, +32 on 2nd instr), chunk tid&7,
    // source chunk xor-swizzled by row&7.
    int srow = tid >> 3;
    int kcs = ((tid & 7) ^ (srow & 7)) * 8;
    const half_t* gK = qkv + (size_t)(b * 2048 + k0g + srow) * 768 + 256 + h * 64 + kcs;
    const half_t* gV = vt + (size_t)(bh * 64 + srow) * 2048 + k0g + kcs;

    // issue order matters: K loads first (bottom vmcnt(2) leaves V in flight)
    auto stage = [&](int it2) {
        int bb = it2 & 1;
        const half_t* gKt = gK + (size_t)(it2 * 64) * 768;
        const half_t* gVt = gV + it2 * 64;
        gload16(gKt,                     &Ks[bb][w * 512]);
        gload16(gKt + (size_t)32 * 768,  &Ks[bb][2048 + w * 512]);
        gload16(gVt,                     &Vts[bb][w * 512]);
        gload16(gVt + 32 * 2048,         &Vts[bb][2048 + w * 512]);
    };

    f32x4 O[4];
    #pragma unroll
    for (int i = 0; i < 4; ++i) O[i] = (f32x4)(0.f);
    float mrow = -1e30f, lrow = 0.f;

    int rx = c & 7;

    // prologue: tile 0 staged, full drain once.
    stage(0);
    __syncthreads();

    for (int it = 0; it < 16; ++it) {
        int ktg = k0g + it * 64;
        if (it < 15) stage(it + 1);               // prefetch into other buffer
        const half_t* Kb = Ks[it & 1];
        const half_t* Vb = Vts[it & 1];

        // S^T = K Q^T : D[key = kb*16 + quad*4+rg, q = c]
        f32x4 ST[4];
        __builtin_amdgcn_s_setprio(1);
        #pragma unroll
        for (int kb = 0; kb < 4; ++kb) {
            int row = kb * 16 + c;
            half8 kf0 = *(const half8*)&Kb[row * 64 + (quad ^ rx) * 8];
            half8 kf1 = *(const half8*)&Kb[row * 64 + ((quad + 4) ^ rx) * 8];
            f32x4 a = (f32x4)(0.f);
            a = __builtin_amdgcn_mfma_f32_16x16x32_f16(kf0, qf0, a, 0, 0, 0);
            a = __builtin_amdgcn_mfma_f32_16x16x32_f16(kf1, qf1, a, 0, 0, 0);
            ST[kb] = a;
        }
        __builtin_amdgcn_s_setprio(0);

        // bias: near tiles gather from btab (L2-resident); far tiles fold
        // the saturated constant cb into madj.
        float cb;
        if (ktg >= q0 + 191) {
            cb = cpos;
        } else if (ktg + 191 <= q0) {
            cb = cneg;
        } else {
            cb = 0.f;
            const float* bp = bpt + it * 64;
            #pragma unroll
            for (int kb = 0; kb < 4; ++kb)
                #pragma unroll
                for (int rg = 0; rg < 4; ++rg)
                    ST[kb][rg] += bp[kb * 16 + quad * 4 + rg];
        }

        // tile max: in-lane 16 keys + 2 swizzles (lanes sharing q = c)
        float tmax = -1e30f;
        #pragma unroll
        for (int kb = 0; kb < 4; ++kb)
            #pragma unroll
            for (int rg = 0; rg < 4; ++rg) tmax = fmaxf(tmax, ST[kb][rg]);
        tmax += cb;
        tmax = fmaxf(tmax, __shfl_xor(tmax, 16));
        tmax = fmaxf(tmax, __shfl_xor(tmax, 32));

        float mnew = fmaxf(mrow, tmax);
        float alpha = fast_exp2(mrow - mnew);     // per-lane scalar
        mrow = mnew;
        float madj = mnew - cb;

        // p = exp2(S - madj) (max-shifted: fp16-safe), kept IN REGISTERS:
        // pc[kb] is directly the B-operand of PV MFMA #kb (k=quad*4+i, col=c).
        half4 pc[4];
        float lsum = 0.f;
        #pragma unroll
        for (int kb = 0; kb < 4; ++kb) {
            #pragma unroll
            for (int rg = 0; rg < 4; ++rg) {
                float p = fast_exp2(ST[kb][rg] - madj);
                lsum += p;
                pc[kb][rg] = (half_t)p;
            }
        }
        lrow = lrow * alpha + lsum;               // in-lane (shared m)

        // mid sync: own old-V done (4 new loads stay in flight), then all waves
        if (it < 15) { __asm__ __volatile__("s_waitcnt vmcnt(4)" ::: "memory"); }
        else         { __asm__ __volatile__("s_waitcnt vmcnt(0)" ::: "memory"); }
        __builtin_amdgcn_s_barrier();

        // O^T[d, q=c] += V^T P^T via 16x16x16 MFMA. V tile is token-permuted
        // (p = quad*16 + kb*4 + i holds original k = kb*16 + quad*4 + i), so
        // each lane's 16 needed halfs are 2 b128 reads (chunks 2q^rx, 2q+1^rx).
        __builtin_amdgcn_s_setprio(1);
        #pragma unroll
        for (int db = 0; db < 4; ++db) {
            const half_t* vrow = &Vb[(db * 16 + c) * 64];
            half8 v01 = *(const half8*)&vrow[((quad * 2) ^ rx) * 8];       // kb=0,1
            half8 v23 = *(const half8*)&vrow[((quad * 2 + 1) ^ rx) * 8];   // kb=2,3
            f32x4 o = O[db];
            #pragma unroll
            for (int rg = 0; rg < 4; ++rg) o[rg] *= alpha;      // per-lane alpha
            o = __builtin_amdgcn_mfma_f32_16x16x16f16(
                    __builtin_shufflevector(v01, v01, 0, 1, 2, 3), pc[0], o, 0, 0, 0);
            o = __builtin_amdgcn_mfma_f32_16x16x16f16(
                    __builtin_shufflevector(v01, v01, 4, 5, 6, 7), pc[1], o, 0, 0, 0);
            o = __builtin_amdgcn_mfma_f32_16x16x16f16(
                    __builtin_shufflevector(v23, v23, 0, 1, 2, 3), pc[2], o, 0, 0, 0);
            o = __builtin_amdgcn_mfma_f32_16x16x16f16(
                    __builtin_shufflevector(v23, v23, 4, 5, 6, 7), pc[3], o, 0, 0, 0);
            O[db] = o;
        }
        __builtin_amdgcn_s_setprio(0);

        // bottom sync: own K(it+1) done (V(it+1) stays in flight), then all waves
        if (it < 15) {
            __asm__ __volatile__("s_waitcnt vmcnt(2)" ::: "memory");
            __builtin_amdgcn_s_barrier();
        }
    }

    // total l across the 4 quad-lanes (same final m), normalize, store
    lrow += __shfl_xor(lrow, 16);
    lrow += __shfl_xor(lrow, 32);
    float inv = 1.0f / lrow;

    int pb = (bh * 32 + qt) * 2 + s;
    #pragma unroll
    for (int db = 0; db < 4; ++db) {
        half4 pk;
        #pragma unroll
        for (int rg = 0; rg < 4; ++rg) pk[rg] = (half_t)(O[db][rg] * inv);
        *(half4*)&Opart[((size_t)pb * 64 + w * 16 + c) * 64 + db * 16 + quad * 4] = pk;
    }
    if (quad == 0) {
        ml[pb * 128 + w * 16 + c] = mrow;
        ml[pb * 128 + 64 + w * 16 + c] = lrow;
    }
}

// ---------------------------------------------------------------------------
// merge the two split-K partials -> ab[b*2048+n][h*64+d]
// Partials normalized: out = (w1*O1 + w2*O2), w_i = 2^(m_i-m) * l_i / Z.
// ---------------------------------------------------------------------------
__global__ __launch_bounds__(256) void merge(const half_t* __restrict__ Opart,
                                             const float* __restrict__ ml,
                                             half_t* __restrict__ ab) {
    int bq = blockIdx.x;            // bh*32 + qt
    int bh = bq >> 5, qt = bq & 31;
    int b = bh >> 2, h = bh & 3;
    int row = threadIdx.x >> 2;
    int cg = (threadIdx.x & 3) * 16;
    int p0 = bq * 2, p1 = p0 + 1;
    float m1 = ml[p0 * 128 + row], l1 = ml[p0 * 128 + 64 + row];
    float m2 = ml[p1 * 128 + row], l2 = ml[p1 * 128 + 64 + row];
    float m = fmaxf(m1, m2);
    float a1 = __builtin_amdgcn_exp2f(m1 - m) * l1;
    float a2 = __builtin_amdgcn_exp2f(m2 - m) * l2;
    float inv = 1.f / (a1 + a2);
    float w1 = a1 * inv, w2 = a2 * inv;
    const half8* o1 = (const half8*)&Opart[((size_t)p0 * 64 + row) * 64 + cg];
    const half8* o2 = (const half8*)&Opart[((size_t)p1 * 64 + row) * 64 + cg];
    half_t* dst = ab + (size_t)(b * 2048 + qt * 64 + row) * 256 + h * 64 + cg;
    #pragma unroll
    for (int v = 0; v < 2; ++v) {
        half8 x = o1[v], y = o2[v], o;
        #pragma unroll
        for (int j = 0; j < 8; ++j)
            o[j] = (half_t)((float)x[j] * w1 + (float)y[j] * w2);
        *(half8*)(dst + v * 8) = o;
    }
}

// ---------------------------------------------------------------------------
// Launch. ws: Wqkv 1.5M | Wo_e .5M | btab 64K | hsh 16M | qkv 12M | vt 4M
// hsh region reused after QKV GEMM: Opart (8.4M) @0, ml (.5M) @8.4M, ab (4M) @9M
// ---------------------------------------------------------------------------
extern "C" void kernel_launch(void* const* d_in, const int* in_sizes, int n_in,
                              void* d_out, int out_size, void* d_ws, size_t ws_size,
                              hipStream_t stream) {
    (void)in_sizes; (void)n_in; (void)out_size; (void)ws_size;
    const float* hs = (const float*)d_in[0];
    const float* Wq = (const float*)d_in[1];
    const float* Wk = (const float*)d_in[2];
    const float* Wv = (const float*)d_in[3];
    const float* Wo = (const float*)d_in[4];
    const float* rb = (const float*)d_in[5];

    char* p = (char*)d_ws;
    half_t* Wqkv = (half_t*)p;            p += 768 * 1024 * 2;
    half_t* Wo_e = (half_t*)p;            p += 1024 * 256 * 2;
    float*  btab = (float*)p;             p += 4 * 4096 * 4;
    char*   hshp = p;                     p += (size_t)8192 * 1024 * 2;
    half_t* qkv  = (half_t*)p;            p += (size_t)8192 * 768 * 2;
    half_t* vt   = (half_t*)p;            p += (size_t)16 * 64 * 2048 * 2;
    half_t* hsh   = (half_t*)hshp;
    half_t* Opart = (half_t*)hshp;                               // 8.4 MB
    float*  mlbuf = (float*)(hshp + (size_t)1024 * 64 * 64 * 2); // 0.5 MB
    half_t* ab    = (half_t*)(hshp + (size_t)9 * 1024 * 1024);   // 4 MB
    float*  out  = (float*)d_out;

    // fused cvt (blocks 0..4095) + weight/bias prep (blocks 4096..7167)
    prep<<<7168, 256, 0, stream>>>(hs, Wq, Wk, Wv, Wo, rb, hsh, Wqkv, Wo_e, btab);

    // qkv[8192,768] = hsh * Wqkv^T; V column-blocks go straight to vt (fused
    // transpose + token permutation). 128x64 tiles: 768 blocks = 3/CU
    // (measured best vs BN=128's 2/CU — R10 A/B).
    gemm_nt_mfma<64><<<12 * 64, 256, 0, stream>>>(hsh, Wqkv, qkv, 768, 1024, 1, vt);

    // split-K=2 flash attention (1024 blocks, 4/CU, XCD group clustering)
    attn<<<1024, 256, 0, stream>>>(qkv, vt, btab, Opart, mlbuf);
    merge<<<512, 256, 0, stream>>>(Opart, mlbuf, ab);

    // out[8192,1024] = ab[8192,256] * Wo_e[1024,256]^T; 128x128 tiles,
    // grid 8x64 = 512 blocks = 2/CU balanced.
    gemm_nt_mfma<128><<<8 * 64, 256, 0, stream>>>(ab, Wo_e, out, 1024, 256, 0, nullptr);
}